// Round 6
// baseline (618.534 us; speedup 1.0000x reference)
//
#include <hip/hip_runtime.h>
#include <cstddef>

namespace nl {
constexpr int B = 2, C = 3, H = 63, W = 63, K = 7;
constexpr int NH = 57, NW = 57, N = NH * NW;      // 3249
constexpr int KS = 147, KSP = 160, NPAD = 3328;
constexpr int SPLITS = 8;
constexpr int MCHUNK = NPAD / SPLITS;             // 416
constexpr int MSTEPS = MCHUNK / 32;               // 13
constexpr size_t SZ_X   = (size_t)B * KSP * NPAD; // 1,064,960 floats
constexpr size_t OFF_XR = 0;                      // ref patches (from y), fp32 [b][k][n]
constexpr size_t OFF_XIB = SZ_X;                  // inp patches (from x), bf16 [b][k][m]; SZ_X ushorts = SZ_X/2 float slots
constexpr size_t OFF_SQ = OFF_XIB + SZ_X / 2;
constexpr size_t OFF_HD = OFF_SQ + (size_t)B * NPAD;
constexpr size_t OFF_BLK = OFF_HD + (size_t)B * NPAD;
constexpr size_t OFF_S1 = OFF_BLK + (size_t)B * NPAD;  // sum e (per n)
constexpr size_t OFF_S2 = OFF_S1 + (size_t)B * NPAD;   // sum e*blk (per n)
constexpr size_t OFF_BIMG = OFF_S2 + (size_t)B * NPAD;
constexpr size_t OFF_ATT = OFF_BIMG + 8192;            // e = exp(score) at [b][n][m] fp32
constexpr size_t SZ_ATT = (size_t)B * NPAD * NPAD;
constexpr size_t OFF_OUTA = OFF_ATT + SZ_ATT;          // atomic accum [b][KSP][n] fp32
}
using namespace nl;

typedef __attribute__((ext_vector_type(8))) short short8;
typedef __attribute__((ext_vector_type(4))) float floatx4;

__device__ inline unsigned short f2bf(float f) {
  unsigned int u = __float_as_uint(f);
  unsigned int r = (u + 0x7FFFu + ((u >> 16) & 1u)) >> 16;
  return (unsigned short)r;
}

// ---------------- block detect (sobel + angle test) ----------------
__global__ __launch_bounds__(256) void nl_block(const float* __restrict__ x,
                                                const float* __restrict__ y,
                                                float* __restrict__ bimg) {
  int idx = blockIdx.x * 256 + threadIdx.x;
  if (idx >= B * H * W) return;
  int q = idx % W, t = idx / W;
  int p = t % H, b = t / H;
  float gx[3][3], gy[3][3];
#pragma unroll
  for (int dy = 0; dy < 3; ++dy)
#pragma unroll
    for (int dx = 0; dx < 3; ++dx) {
      int pp = p + dy - 1, qq = q + dx - 1;
      float vx = 0.f, vy = 0.f;
      if (pp >= 0 && pp < H && qq >= 0 && qq < W) {
        int base = (b * C * H + pp) * W + qq;
        vx = 0.299f * x[base] + 0.587f * x[base + H * W] + 0.114f * x[base + 2 * H * W];
        vy = 0.299f * y[base] + 0.587f * y[base + H * W] + 0.114f * y[base + 2 * H * W];
      }
      gx[dy][dx] = vx; gy[dy][dx] = vy;
    }
  float in_gx = (q == W - 1) ? 1.f : (-gx[0][0] + gx[0][2] - 2.f * gx[1][0] + 2.f * gx[1][2] - gx[2][0] + gx[2][2]);
  float in_gy = (p == H - 1) ? 1.f : (-gx[0][0] - 2.f * gx[0][1] - gx[0][2] + gx[2][0] + 2.f * gx[2][1] + gx[2][2]);
  float rf_gx = (q == W - 1) ? 1.f : (-gy[0][0] + gy[0][2] - 2.f * gy[1][0] + 2.f * gy[1][2] - gy[2][0] + gy[2][2]);
  float rf_gy = (p == H - 1) ? 1.f : (-gy[0][0] - 2.f * gy[0][1] - gy[0][2] + gy[2][0] + 2.f * gy[2][1] + gy[2][2]);
  float n_in = sqrtf(in_gx * in_gx + in_gy * in_gy);
  float n_rf = sqrtf(rf_gx * rf_gx + rf_gy * rf_gy);
  float cosv = (in_gx * rf_gx + in_gy * rf_gy + 0.001f) / (n_in * n_rf + 0.001f);
  float det = (n_in >= 29.f) ? ((n_rf >= 29.f) ? (1.f - cosv) : 1.f) : 0.f;
  bimg[(b * H + p) * W + q] = 1.f - det;
}

// ---------------- blk_p: 7x7 box mean of block image (0 for m>=N) ----------------
__global__ __launch_bounds__(256) void nl_blkp(const float* __restrict__ bimg,
                                               float* __restrict__ blk) {
  int idx = blockIdx.x * 256 + threadIdx.x;
  if (idx >= B * NPAD) return;
  int n = idx % NPAD, b = idx / NPAD;
  float v = 0.f;
  if (n < N) {
    int i = n / NW, j = n % NW;
    float s = 0.f;
#pragma unroll
    for (int ky = 0; ky < K; ++ky)
#pragma unroll
      for (int kx = 0; kx < K; ++kx)
        s += bimg[(b * H + i + ky) * W + (j + kx)];
    v = s * (1.f / 49.f);
  }
  blk[idx] = v;
}

// ---------------- im2col: Xr fp32 [b][k][n] from y; Xi bf16 [b][k][m] from x ----------------
__global__ __launch_bounds__(256) void nl_im2col(const float* __restrict__ x,
                                                 const float* __restrict__ y,
                                                 float* __restrict__ ws) {
  size_t idx = (size_t)blockIdx.x * 256 + threadIdx.x;
  if (idx >= 2 * SZ_X) return;
  if (idx < SZ_X) {
    int n = (int)(idx % NPAD);
    int r1 = (int)(idx / NPAD);
    int k = r1 % KSP, b = r1 / KSP;
    float v = 0.f;
    if (k < KS && n < N) {
      int c = k / 49, r = k % 49;
      int ky = r / 7, kx = r % 7;
      int i = n / NW, j = n % NW;
      v = y[((b * C + c) * H + (i + ky)) * W + (j + kx)];
    }
    ws[OFF_XR + idx] = v;
  } else {
    size_t i2 = idx - SZ_X;
    int n = (int)(i2 % NPAD);
    int r1 = (int)(i2 / NPAD);
    int k = r1 % KSP, b = r1 / KSP;
    float v = 0.f;
    if (k < KS && n < N) {
      int c = k / 49, r = k % 49;
      int ky = r / 7, kx = r % 7;
      int i = n / NW, j = n % NW;
      v = x[((b * C + c) * H + (i + ky)) * W + (j + kx)];
    }
    ((unsigned short*)(ws + OFF_XIB))[i2] = f2bf(v);
  }
}

// ---------------- per-query sq, h-network; zero s1/s2 ----------------
__global__ __launch_bounds__(256) void nl_sqh(const float* __restrict__ ws_xr,
                                              const float* __restrict__ w1,
                                              const float* __restrict__ b1,
                                              const float* __restrict__ w2,
                                              const float* __restrict__ b2,
                                              float* __restrict__ sq,
                                              float* __restrict__ hd,
                                              float* __restrict__ s1g,
                                              float* __restrict__ s2g) {
  int idx = blockIdx.x * 256 + threadIdx.x;
  if (idx >= B * NPAD) return;
  int n = idx % NPAD, b = idx / NPAD;
  s1g[idx] = 0.f;
  s2g[idx] = 0.f;
  if (n >= N) { sq[idx] = 0.f; hd[idx] = 1.f; return; }
  const float* Xr = ws_xr + (size_t)b * KSP * NPAD + n;
  float s = 0.f, h0 = b1[0], h1 = b1[1], h2 = b1[2];
  for (int k = 0; k < KS; ++k) {
    float v = Xr[(size_t)k * NPAD];
    s += v * v;
    h0 += v * w1[k];
    h1 += v * w1[KS + k];
    h2 += v * w1[2 * KS + k];
  }
  h0 = fmaxf(h0, 0.f); h1 = fmaxf(h1, 0.f); h2 = fmaxf(h2, 0.f);
  float h = h0 * w2[0] + h1 * w2[1] + h2 * w2[2] + b2[0];
  sq[idx] = s;
  hd[idx] = h * h + 1.f;
}

// ---------------- GEMM1 (symmetric-half): att[n][m] = exp((2XY - sq_n - sq_m)/hd_n)
//                  fused row-sum atomics: s1[n] += e (m<N), s2[n] += e*blk[m] ----------------
__global__ __launch_bounds__(256) void nl_gemm1(const float* __restrict__ ws_xr,
                                                const float* __restrict__ sq,
                                                const float* __restrict__ hd,
                                                const float* __restrict__ blk,
                                                float* __restrict__ att,
                                                float* __restrict__ s1g,
                                                float* __restrict__ s2g) {
  int bx = blockIdx.x, by = blockIdx.y;
  if (bx < by) return;  // compute upper triangle tiles; both orientations written
  __shared__ float As[32][128];
  __shared__ float Bs[32][128];
  int b = blockIdx.z;
  const float* Xb = ws_xr + (size_t)b * KSP * NPAD;
  int row0 = by * 128, col0 = bx * 128;
  int t = threadIdx.x;
  int tr = t >> 4, tc = t & 15;
  float acc[8][8];
#pragma unroll
  for (int i = 0; i < 8; ++i)
#pragma unroll
    for (int j = 0; j < 8; ++j) acc[i][j] = 0.f;

  for (int kt = 0; kt < KSP; kt += 32) {
#pragma unroll
    for (int u = 0; u < 4; ++u) {
      int e = t + u * 256;
      int kk = e >> 5, cc = e & 31;
      float4 va = *(const float4*)(Xb + (size_t)(kt + kk) * NPAD + row0 + cc * 4);
      *(float4*)(&As[kk][cc * 4]) = va;
      float4 vb = *(const float4*)(Xb + (size_t)(kt + kk) * NPAD + col0 + cc * 4);
      *(float4*)(&Bs[kk][cc * 4]) = vb;
    }
    __syncthreads();
#pragma unroll
    for (int kk = 0; kk < 32; ++kk) {
      float a[8], bb[8];
      *(float4*)(&a[0]) = *(const float4*)(&As[kk][tr * 4]);
      *(float4*)(&a[4]) = *(const float4*)(&As[kk][64 + tr * 4]);
      *(float4*)(&bb[0]) = *(const float4*)(&Bs[kk][tc * 4]);
      *(float4*)(&bb[4]) = *(const float4*)(&Bs[kk][64 + tc * 4]);
#pragma unroll
      for (int i = 0; i < 8; ++i)
#pragma unroll
        for (int j = 0; j < 8; ++j) acc[i][j] = fmaf(a[i], bb[j], acc[i][j]);
    }
    __syncthreads();
  }
  int rI[8], cJ[8];
#pragma unroll
  for (int i = 0; i < 4; ++i) { rI[i] = row0 + tr * 4 + i; rI[i + 4] = row0 + 64 + tr * 4 + i; }
#pragma unroll
  for (int j = 0; j < 4; ++j) { cJ[j] = col0 + tc * 4 + j; cJ[j + 4] = col0 + 64 + tc * 4 + j; }
  float sqn[8], hin[8], sqm[8], him[8], blkn[8], blkm[8];
#pragma unroll
  for (int i = 0; i < 8; ++i) {
    sqn[i] = sq[b * NPAD + rI[i]];
    hin[i] = 1.f / hd[b * NPAD + rI[i]];
    blkn[i] = blk[b * NPAD + rI[i]];
  }
#pragma unroll
  for (int j = 0; j < 8; ++j) {
    sqm[j] = sq[b * NPAD + cJ[j]];
    him[j] = 1.f / hd[b * NPAD + cJ[j]];
    blkm[j] = blk[b * NPAD + cJ[j]];
  }
  // direct tile: att rows n = rI[i], cols m = cJ[j], divisor hd_n = 1/hin
#pragma unroll
  for (int i = 0; i < 8; ++i) {
    float v[8];
    float a1 = 0.f, a2 = 0.f;
#pragma unroll
    for (int j = 0; j < 8; ++j) {
      float e = __expf((2.f * acc[i][j] - sqn[i] - sqm[j]) * hin[i]);
      v[j] = e;
      if (cJ[j] < N) a1 += e;
      a2 += e * blkm[j];
    }
    float* arow = att + ((size_t)b * NPAD + rI[i]) * NPAD;
    *(float4*)(arow + col0 + tc * 4) = *(float4*)(&v[0]);
    *(float4*)(arow + col0 + 64 + tc * 4) = *(float4*)(&v[4]);
    atomicAdd(s1g + b * NPAD + rI[i], a1);
    atomicAdd(s2g + b * NPAD + rI[i], a2);
  }
  if (bx != by) {
    // mirror tile: att rows n = cJ[j], cols m = rI[i], divisor hd_n = 1/him
#pragma unroll
    for (int j = 0; j < 8; ++j) {
      float v[8];
      float a1 = 0.f, a2 = 0.f;
#pragma unroll
      for (int i = 0; i < 8; ++i) {
        float e = __expf((2.f * acc[i][j] - sqn[i] - sqm[j]) * him[j]);
        v[i] = e;
        if (rI[i] < N) a1 += e;
        a2 += e * blkn[i];
      }
      float* arow = att + ((size_t)b * NPAD + cJ[j]) * NPAD;
      *(float4*)(arow + row0 + tr * 4) = *(float4*)(&v[0]);
      *(float4*)(arow + row0 + 64 + tr * 4) = *(float4*)(&v[4]);
      atomicAdd(s1g + b * NPAD + cJ[j], a1);
      atomicAdd(s2g + b * NPAD + cJ[j], a2);
    }
  }
}

// ---------------- GEMM2 (bf16 MFMA): out[k,n] += P[n,m]*Xi[k,m], P = e*blk, scale dinv[n]
//                  D = A(Xi: k x m) * B(P: m x n); 128n x 160k x 416m per block ----------------
__global__ __launch_bounds__(256) void nl_gemm2(const float* __restrict__ att,
                                                const unsigned short* __restrict__ xib,
                                                const float* __restrict__ s1g,
                                                const float* __restrict__ s2g,
                                                const float* __restrict__ blk,
                                                float* __restrict__ outp0) {
  __shared__ unsigned short Plds[128][32];  // [n][m] bf16
  __shared__ unsigned short Xlds[160][32];  // [k][m] bf16
  __shared__ float dil[128];
  int b = blockIdx.z;
  int n0 = blockIdx.x * 128;
  int m0 = blockIdx.y * MCHUNK;
  const float* attb = att + (size_t)b * NPAD * NPAD;
  const unsigned short* Xib = xib + (size_t)b * KSP * NPAD;
  const float* blkb = blk + b * NPAD;
  int t = threadIdx.x;
  if (t < 128) {
    int nn = n0 + t;
    float d = s2g[b * NPAD + nn] + 0.001f * s1g[b * NPAD + nn];
    dil[t] = (nn < N) ? 1.f / d : 0.f;
  }
  int lane = t & 63, wv = t >> 6;
  int li = lane & 15, lg = lane >> 4;
  int pq = t & 7, pn0 = t >> 3;  // staging maps (att: 4 rounds, Xi: 5 rounds)

  floatx4 acc[2][10];
#pragma unroll
  for (int a = 0; a < 2; ++a)
#pragma unroll
    for (int j = 0; j < 10; ++j) acc[a][j] = (floatx4)0.f;

  float4 pa[4];
  ushort4 px[5];
  float4 bl4;
  // prologue loads (it = 0)
  bl4 = *(const float4*)(blkb + m0 + pq * 4);
#pragma unroll
  for (int u = 0; u < 4; ++u)
    pa[u] = *(const float4*)(attb + (size_t)(n0 + pn0 + u * 32) * NPAD + m0 + pq * 4);
#pragma unroll
  for (int u = 0; u < 5; ++u)
    px[u] = *(const ushort4*)(Xib + (size_t)(pn0 + u * 32) * NPAD + m0 + pq * 4);

  for (int it = 0; it < MSTEPS; ++it) {
    __syncthreads();
    // stage: att f32 -> (e*blk) bf16 into Plds[n][m]; Xi bf16 into Xlds[k][m]
#pragma unroll
    for (int u = 0; u < 4; ++u) {
      ushort4 o;
      o.x = f2bf(pa[u].x * bl4.x);
      o.y = f2bf(pa[u].y * bl4.y);
      o.z = f2bf(pa[u].z * bl4.z);
      o.w = f2bf(pa[u].w * bl4.w);
      *(ushort4*)(&Plds[pn0 + u * 32][pq * 4]) = o;
    }
#pragma unroll
    for (int u = 0; u < 5; ++u)
      *(ushort4*)(&Xlds[pn0 + u * 32][pq * 4]) = px[u];
    __syncthreads();
    if (it + 1 < MSTEPS) {
      int mn = m0 + (it + 1) * 32;
      bl4 = *(const float4*)(blkb + mn + pq * 4);
#pragma unroll
      for (int u = 0; u < 4; ++u)
        pa[u] = *(const float4*)(attb + (size_t)(n0 + pn0 + u * 32) * NPAD + mn + pq * 4);
#pragma unroll
      for (int u = 0; u < 5; ++u)
        px[u] = *(const ushort4*)(Xib + (size_t)(pn0 + u * 32) * NPAD + mn + pq * 4);
    }
    // compute: wave wv owns n-frags {2wv, 2wv+1} x k-frags 0..9
    short8 bf2[2];
#pragma unroll
    for (int a = 0; a < 2; ++a)
      bf2[a] = *(const short8*)(&Plds[32 * wv + 16 * a + li][8 * lg]);
#pragma unroll
    for (int j = 0; j < 10; ++j) {
      short8 af = *(const short8*)(&Xlds[16 * j + li][8 * lg]);
#pragma unroll
      for (int a = 0; a < 2; ++a)
        acc[a][j] = __builtin_amdgcn_mfma_f32_16x16x32_bf16(af, bf2[a], acc[a][j], 0, 0, 0);
    }
  }
  float* outp = outp0 + (size_t)b * KSP * NPAD;
#pragma unroll
  for (int a = 0; a < 2; ++a) {
    int nloc = 32 * wv + 16 * a + li;
    int n = n0 + nloc;
    float dv = dil[nloc];
#pragma unroll
    for (int j = 0; j < 10; ++j) {
#pragma unroll
      for (int r = 0; r < 4; ++r) {
        int k = 16 * j + 4 * lg + r;
        atomicAdd(outp + (size_t)k * NPAD + n, acc[a][j][r] * dv);
      }
    }
  }
}

// ---------------- fold (overlap-add adjoint of im2col) + weight divide ----------------
__global__ __launch_bounds__(256) void nl_fold(const float* __restrict__ outA,
                                               float* __restrict__ out) {
  int idx = blockIdx.x * 256 + threadIdx.x;
  if (idx >= B * C * H * W) return;
  int q = idx % W, t = idx / W;
  int p = t % H, t2 = t / H;
  int c = t2 % C, b = t2 / C;
  float s = 0.f;
#pragma unroll
  for (int ky = 0; ky < K; ++ky) {
    int iy = p - ky;
    if (iy < 0 || iy >= NH) continue;
#pragma unroll
    for (int kx = 0; kx < K; ++kx) {
      int jx = q - kx;
      if (jx < 0 || jx >= NW) continue;
      size_t o = ((size_t)(b * KSP + c * 49 + ky * 7 + kx)) * NPAD + iy * NW + jx;
      s += outA[o];
    }
  }
  int cy = min(p, 6) - max(0, p - 56) + 1;
  int cx = min(q, 6) - max(0, q - 56) + 1;
  out[idx] = s / (float)(cy * cx);
}

extern "C" void kernel_launch(void* const* d_in, const int* in_sizes, int n_in,
                              void* d_out, int out_size, void* d_ws, size_t ws_size,
                              hipStream_t stream) {
  const float* x = (const float*)d_in[0];
  const float* y = (const float*)d_in[1];
  const float* w1 = (const float*)d_in[2];
  const float* b1 = (const float*)d_in[3];
  const float* w2 = (const float*)d_in[4];
  const float* b2 = (const float*)d_in[5];
  float* ws = (float*)d_ws;
  float* out = (float*)d_out;

  float* Xr = ws + OFF_XR;
  unsigned short* Xib = (unsigned short*)(ws + OFF_XIB);
  float* sq = ws + OFF_SQ;
  float* hd = ws + OFF_HD;
  float* blk = ws + OFF_BLK;
  float* s1g = ws + OFF_S1;
  float* s2g = ws + OFF_S2;
  float* bimg = ws + OFF_BIMG;
  float* att = ws + OFF_ATT;
  float* outA = ws + OFF_OUTA;

  hipMemsetAsync(outA, 0, SZ_X * sizeof(float), stream);

  nl_block<<<(B * H * W + 255) / 256, 256, 0, stream>>>(x, y, bimg);
  nl_im2col<<<(int)((2 * SZ_X + 255) / 256), 256, 0, stream>>>(x, y, ws);
  nl_blkp<<<(B * NPAD + 255) / 256, 256, 0, stream>>>(bimg, blk);
  nl_sqh<<<(B * NPAD + 255) / 256, 256, 0, stream>>>(Xr, w1, b1, w2, b2, sq, hd, s1g, s2g);
  nl_gemm1<<<dim3(NPAD / 128, NPAD / 128, B), 256, 0, stream>>>(Xr, sq, hd, blk, att, s1g, s2g);
  nl_gemm2<<<dim3(NPAD / 128, SPLITS, B), 256, 0, stream>>>(att, Xib, s1g, s2g, blk, outA);
  nl_fold<<<(B * C * H * W + 255) / 256, 256, 0, stream>>>(outA, out);
}

// Round 7
// 224.516 us; speedup vs baseline: 2.7550x; 2.7550x over previous
//
#include <hip/hip_runtime.h>
#include <cstddef>

namespace nl {
constexpr int B = 2, C = 3, H = 63, W = 63, K = 7;
constexpr int NH = 57, NW = 57, N = NH * NW;      // 3249
constexpr int KS = 147, KSP = 160, NPAD = 3328;
constexpr int SPLITS = 8;
constexpr int MCHUNK = NPAD / SPLITS;             // 416
constexpr int MSTEPS = MCHUNK / 32;               // 13
constexpr size_t SZ_X   = (size_t)B * KSP * NPAD; // 1,064,960 floats
constexpr size_t OFF_XR = 0;                      // ref patches (from y), fp32 [b][k][n]
constexpr size_t OFF_XIB = SZ_X;                  // inp patches (from x), bf16 [b][k][m]
constexpr size_t OFF_SQ = OFF_XIB + SZ_X / 2;
constexpr size_t OFF_HD = OFF_SQ + (size_t)B * NPAD;
constexpr size_t OFF_BLK = OFF_HD + (size_t)B * NPAD;
constexpr size_t OFF_DI = OFF_BLK + (size_t)B * NPAD;  // dinv per n
constexpr size_t OFF_BIMG = OFF_DI + (size_t)B * NPAD;
constexpr size_t OFF_ATT = OFF_BIMG + 8192;            // e = exp(score) at [b][n][m] fp32
constexpr size_t SZ_ATT = (size_t)B * NPAD * NPAD;
constexpr size_t OFF_OUTA = OFF_ATT + SZ_ATT;          // atomic accum [b][KSP][n] fp32
}
using namespace nl;

typedef __attribute__((ext_vector_type(8))) short short8;
typedef __attribute__((ext_vector_type(4))) float floatx4;

__device__ inline unsigned short f2bf(float f) {
  unsigned int u = __float_as_uint(f);
  unsigned int r = (u + 0x7FFFu + ((u >> 16) & 1u)) >> 16;
  return (unsigned short)r;
}

// ---------------- block detect (sobel + angle test) ----------------
__global__ __launch_bounds__(256) void nl_block(const float* __restrict__ x,
                                                const float* __restrict__ y,
                                                float* __restrict__ bimg) {
  int idx = blockIdx.x * 256 + threadIdx.x;
  if (idx >= B * H * W) return;
  int q = idx % W, t = idx / W;
  int p = t % H, b = t / H;
  float gx[3][3], gy[3][3];
#pragma unroll
  for (int dy = 0; dy < 3; ++dy)
#pragma unroll
    for (int dx = 0; dx < 3; ++dx) {
      int pp = p + dy - 1, qq = q + dx - 1;
      float vx = 0.f, vy = 0.f;
      if (pp >= 0 && pp < H && qq >= 0 && qq < W) {
        int base = (b * C * H + pp) * W + qq;
        vx = 0.299f * x[base] + 0.587f * x[base + H * W] + 0.114f * x[base + 2 * H * W];
        vy = 0.299f * y[base] + 0.587f * y[base + H * W] + 0.114f * y[base + 2 * H * W];
      }
      gx[dy][dx] = vx; gy[dy][dx] = vy;
    }
  float in_gx = (q == W - 1) ? 1.f : (-gx[0][0] + gx[0][2] - 2.f * gx[1][0] + 2.f * gx[1][2] - gx[2][0] + gx[2][2]);
  float in_gy = (p == H - 1) ? 1.f : (-gx[0][0] - 2.f * gx[0][1] - gx[0][2] + gx[2][0] + 2.f * gx[2][1] + gx[2][2]);
  float rf_gx = (q == W - 1) ? 1.f : (-gy[0][0] + gy[0][2] - 2.f * gy[1][0] + 2.f * gy[1][2] - gy[2][0] + gy[2][2]);
  float rf_gy = (p == H - 1) ? 1.f : (-gy[0][0] - 2.f * gy[0][1] - gy[0][2] + gy[2][0] + 2.f * gy[2][1] + gy[2][2]);
  float n_in = sqrtf(in_gx * in_gx + in_gy * in_gy);
  float n_rf = sqrtf(rf_gx * rf_gx + rf_gy * rf_gy);
  float cosv = (in_gx * rf_gx + in_gy * rf_gy + 0.001f) / (n_in * n_rf + 0.001f);
  float det = (n_in >= 29.f) ? ((n_rf >= 29.f) ? (1.f - cosv) : 1.f) : 0.f;
  bimg[(b * H + p) * W + q] = 1.f - det;
}

// ---------------- blk_p: 7x7 box mean of block image (0 for m>=N) ----------------
__global__ __launch_bounds__(256) void nl_blkp(const float* __restrict__ bimg,
                                               float* __restrict__ blk) {
  int idx = blockIdx.x * 256 + threadIdx.x;
  if (idx >= B * NPAD) return;
  int n = idx % NPAD, b = idx / NPAD;
  float v = 0.f;
  if (n < N) {
    int i = n / NW, j = n % NW;
    float s = 0.f;
#pragma unroll
    for (int ky = 0; ky < K; ++ky)
#pragma unroll
      for (int kx = 0; kx < K; ++kx)
        s += bimg[(b * H + i + ky) * W + (j + kx)];
    v = s * (1.f / 49.f);
  }
  blk[idx] = v;
}

// ---------------- im2col: Xr fp32 [b][k][n] from y; Xi bf16 [b][k][m] from x ----------------
__global__ __launch_bounds__(256) void nl_im2col(const float* __restrict__ x,
                                                 const float* __restrict__ y,
                                                 float* __restrict__ ws) {
  size_t idx = (size_t)blockIdx.x * 256 + threadIdx.x;
  if (idx >= 2 * SZ_X) return;
  if (idx < SZ_X) {
    int n = (int)(idx % NPAD);
    int r1 = (int)(idx / NPAD);
    int k = r1 % KSP, b = r1 / KSP;
    float v = 0.f;
    if (k < KS && n < N) {
      int c = k / 49, r = k % 49;
      int ky = r / 7, kx = r % 7;
      int i = n / NW, j = n % NW;
      v = y[((b * C + c) * H + (i + ky)) * W + (j + kx)];
    }
    ws[OFF_XR + idx] = v;
  } else {
    size_t i2 = idx - SZ_X;
    int n = (int)(i2 % NPAD);
    int r1 = (int)(i2 / NPAD);
    int k = r1 % KSP, b = r1 / KSP;
    float v = 0.f;
    if (k < KS && n < N) {
      int c = k / 49, r = k % 49;
      int ky = r / 7, kx = r % 7;
      int i = n / NW, j = n % NW;
      v = x[((b * C + c) * H + (i + ky)) * W + (j + kx)];
    }
    ((unsigned short*)(ws + OFF_XIB))[i2] = f2bf(v);
  }
}

// ---------------- per-query sq, h-network ----------------
__global__ __launch_bounds__(256) void nl_sqh(const float* __restrict__ ws_xr,
                                              const float* __restrict__ w1,
                                              const float* __restrict__ b1,
                                              const float* __restrict__ w2,
                                              const float* __restrict__ b2,
                                              float* __restrict__ sq,
                                              float* __restrict__ hd) {
  int idx = blockIdx.x * 256 + threadIdx.x;
  if (idx >= B * NPAD) return;
  int n = idx % NPAD, b = idx / NPAD;
  if (n >= N) { sq[idx] = 0.f; hd[idx] = 1.f; return; }
  const float* Xr = ws_xr + (size_t)b * KSP * NPAD + n;
  float s = 0.f, h0 = b1[0], h1 = b1[1], h2 = b1[2];
  for (int k = 0; k < KS; ++k) {
    float v = Xr[(size_t)k * NPAD];
    s += v * v;
    h0 += v * w1[k];
    h1 += v * w1[KS + k];
    h2 += v * w1[2 * KS + k];
  }
  h0 = fmaxf(h0, 0.f); h1 = fmaxf(h1, 0.f); h2 = fmaxf(h2, 0.f);
  float h = h0 * w2[0] + h1 * w2[1] + h2 * w2[2] + b2[0];
  sq[idx] = s;
  hd[idx] = h * h + 1.f;
}

// ---------------- GEMM1 (symmetric-half): att[n][m] = exp((2XY - sq_n - sq_m)/hd_n) ----------------
__global__ __launch_bounds__(256) void nl_gemm1(const float* __restrict__ ws_xr,
                                                const float* __restrict__ sq,
                                                const float* __restrict__ hd,
                                                float* __restrict__ att) {
  int bx = blockIdx.x, by = blockIdx.y;
  if (bx < by) return;  // compute upper triangle tiles; both orientations written
  __shared__ float As[32][128];
  __shared__ float Bs[32][128];
  int b = blockIdx.z;
  const float* Xb = ws_xr + (size_t)b * KSP * NPAD;
  int row0 = by * 128, col0 = bx * 128;
  int t = threadIdx.x;
  int tr = t >> 4, tc = t & 15;
  float acc[8][8];
#pragma unroll
  for (int i = 0; i < 8; ++i)
#pragma unroll
    for (int j = 0; j < 8; ++j) acc[i][j] = 0.f;

  for (int kt = 0; kt < KSP; kt += 32) {
#pragma unroll
    for (int u = 0; u < 4; ++u) {
      int e = t + u * 256;
      int kk = e >> 5, cc = e & 31;
      float4 va = *(const float4*)(Xb + (size_t)(kt + kk) * NPAD + row0 + cc * 4);
      *(float4*)(&As[kk][cc * 4]) = va;
      float4 vb = *(const float4*)(Xb + (size_t)(kt + kk) * NPAD + col0 + cc * 4);
      *(float4*)(&Bs[kk][cc * 4]) = vb;
    }
    __syncthreads();
#pragma unroll
    for (int kk = 0; kk < 32; ++kk) {
      float a[8], bb[8];
      *(float4*)(&a[0]) = *(const float4*)(&As[kk][tr * 4]);
      *(float4*)(&a[4]) = *(const float4*)(&As[kk][64 + tr * 4]);
      *(float4*)(&bb[0]) = *(const float4*)(&Bs[kk][tc * 4]);
      *(float4*)(&bb[4]) = *(const float4*)(&Bs[kk][64 + tc * 4]);
#pragma unroll
      for (int i = 0; i < 8; ++i)
#pragma unroll
        for (int j = 0; j < 8; ++j) acc[i][j] = fmaf(a[i], bb[j], acc[i][j]);
    }
    __syncthreads();
  }
  int rI[8], cJ[8];
#pragma unroll
  for (int i = 0; i < 4; ++i) { rI[i] = row0 + tr * 4 + i; rI[i + 4] = row0 + 64 + tr * 4 + i; }
#pragma unroll
  for (int j = 0; j < 4; ++j) { cJ[j] = col0 + tc * 4 + j; cJ[j + 4] = col0 + 64 + tc * 4 + j; }
  float sqn[8], hin[8], sqm[8], him[8];
#pragma unroll
  for (int i = 0; i < 8; ++i) { sqn[i] = sq[b * NPAD + rI[i]]; hin[i] = 1.f / hd[b * NPAD + rI[i]]; }
#pragma unroll
  for (int j = 0; j < 8; ++j) { sqm[j] = sq[b * NPAD + cJ[j]]; him[j] = 1.f / hd[b * NPAD + cJ[j]]; }
  // direct tile: att rows n = rI[i], cols m = cJ[j], divisor hd_n
#pragma unroll
  for (int i = 0; i < 8; ++i) {
    float v[8];
#pragma unroll
    for (int j = 0; j < 8; ++j)
      v[j] = __expf((2.f * acc[i][j] - sqn[i] - sqm[j]) * hin[i]);
    float* arow = att + ((size_t)b * NPAD + rI[i]) * NPAD;
    *(float4*)(arow + col0 + tc * 4) = *(float4*)(&v[0]);
    *(float4*)(arow + col0 + 64 + tc * 4) = *(float4*)(&v[4]);
  }
  if (bx != by) {
    // mirror tile: att rows n = cJ[j], cols m = rI[i], divisor hd of cJ
#pragma unroll
    for (int j = 0; j < 8; ++j) {
      float v[8];
#pragma unroll
      for (int i = 0; i < 8; ++i)
        v[i] = __expf((2.f * acc[i][j] - sqn[i] - sqm[j]) * him[j]);
      float* arow = att + ((size_t)b * NPAD + cJ[j]) * NPAD;
      *(float4*)(arow + row0 + tr * 4) = *(float4*)(&v[0]);
      *(float4*)(arow + row0 + 64 + tr * 4) = *(float4*)(&v[4]);
    }
  }
}

// ---------------- row sums of att[n][*]: dinv[n] = 1/(s2 + 0.001*s1) ----------------
__global__ __launch_bounds__(256) void nl_ssum(const float* __restrict__ att,
                                               const float* __restrict__ blk,
                                               float* __restrict__ dinv) {
  int n = blockIdx.x, b = blockIdx.y;
  int tid = threadIdx.x;
  if (n >= N) { if (tid == 0) dinv[b * NPAD + n] = 0.f; return; }
  const float* row = att + ((size_t)b * NPAD + n) * NPAD;
  const float* bl = blk + b * NPAD;
  float s1 = 0.f, s2 = 0.f;
  for (int m = tid; m < N; m += 256) {
    float e = row[m];
    s1 += e;
    s2 += e * bl[m];
  }
  __shared__ float r1[256], r2[256];
  r1[tid] = s1; r2[tid] = s2;
  __syncthreads();
  for (int s = 128; s > 0; s >>= 1) {
    if (tid < s) { r1[tid] += r1[tid + s]; r2[tid] += r2[tid + s]; }
    __syncthreads();
  }
  if (tid == 0) dinv[b * NPAD + n] = 1.f / (r2[0] + 0.001f * r1[0]);
}

// ---------------- GEMM2 (bf16 MFMA): out[k,n] += P[n,m]*Xi[k,m], P = e*blk, scale dinv[n] ----------------
__global__ __launch_bounds__(256) void nl_gemm2(const float* __restrict__ att,
                                                const unsigned short* __restrict__ xib,
                                                const float* __restrict__ dinv,
                                                const float* __restrict__ blk,
                                                float* __restrict__ outp0) {
  __shared__ unsigned short Plds[128][32];  // [n][m] bf16
  __shared__ unsigned short Xlds[160][32];  // [k][m] bf16
  __shared__ float dil[128];
  int b = blockIdx.z;
  int n0 = blockIdx.x * 128;
  int m0 = blockIdx.y * MCHUNK;
  const float* attb = att + (size_t)b * NPAD * NPAD;
  const unsigned short* Xib = xib + (size_t)b * KSP * NPAD;
  const float* blkb = blk + b * NPAD;
  int t = threadIdx.x;
  if (t < 128) dil[t] = dinv[b * NPAD + n0 + t];
  int lane = t & 63, wv = t >> 6;
  int li = lane & 15, lg = lane >> 4;
  int pq = t & 7, pn0 = t >> 3;  // staging maps (att: 4 rounds, Xi: 5 rounds)

  floatx4 acc[2][10];
#pragma unroll
  for (int a = 0; a < 2; ++a)
#pragma unroll
    for (int j = 0; j < 10; ++j) acc[a][j] = (floatx4)0.f;

  float4 pa[4];
  ushort4 px[5];
  float4 bl4;
  bl4 = *(const float4*)(blkb + m0 + pq * 4);
#pragma unroll
  for (int u = 0; u < 4; ++u)
    pa[u] = *(const float4*)(attb + (size_t)(n0 + pn0 + u * 32) * NPAD + m0 + pq * 4);
#pragma unroll
  for (int u = 0; u < 5; ++u)
    px[u] = *(const ushort4*)(Xib + (size_t)(pn0 + u * 32) * NPAD + m0 + pq * 4);

  for (int it = 0; it < MSTEPS; ++it) {
    __syncthreads();
#pragma unroll
    for (int u = 0; u < 4; ++u) {
      ushort4 o;
      o.x = f2bf(pa[u].x * bl4.x);
      o.y = f2bf(pa[u].y * bl4.y);
      o.z = f2bf(pa[u].z * bl4.z);
      o.w = f2bf(pa[u].w * bl4.w);
      *(ushort4*)(&Plds[pn0 + u * 32][pq * 4]) = o;
    }
#pragma unroll
    for (int u = 0; u < 5; ++u)
      *(ushort4*)(&Xlds[pn0 + u * 32][pq * 4]) = px[u];
    __syncthreads();
    if (it + 1 < MSTEPS) {
      int mn = m0 + (it + 1) * 32;
      bl4 = *(const float4*)(blkb + mn + pq * 4);
#pragma unroll
      for (int u = 0; u < 4; ++u)
        pa[u] = *(const float4*)(attb + (size_t)(n0 + pn0 + u * 32) * NPAD + mn + pq * 4);
#pragma unroll
      for (int u = 0; u < 5; ++u)
        px[u] = *(const ushort4*)(Xib + (size_t)(pn0 + u * 32) * NPAD + mn + pq * 4);
    }
    short8 bf2[2];
#pragma unroll
    for (int a = 0; a < 2; ++a)
      bf2[a] = *(const short8*)(&Plds[32 * wv + 16 * a + li][8 * lg]);
#pragma unroll
    for (int j = 0; j < 10; ++j) {
      short8 af = *(const short8*)(&Xlds[16 * j + li][8 * lg]);
#pragma unroll
      for (int a = 0; a < 2; ++a)
        acc[a][j] = __builtin_amdgcn_mfma_f32_16x16x32_bf16(af, bf2[a], acc[a][j], 0, 0, 0);
    }
  }
  float* outp = outp0 + (size_t)b * KSP * NPAD;
#pragma unroll
  for (int a = 0; a < 2; ++a) {
    int nloc = 32 * wv + 16 * a + li;
    int n = n0 + nloc;
    float dv = dil[nloc];
#pragma unroll
    for (int j = 0; j < 10; ++j) {
#pragma unroll
      for (int r = 0; r < 4; ++r) {
        int k = 16 * j + 4 * lg + r;
        atomicAdd(outp + (size_t)k * NPAD + n, acc[a][j][r] * dv);
      }
    }
  }
}

// ---------------- fold (overlap-add adjoint of im2col) + weight divide ----------------
__global__ __launch_bounds__(256) void nl_fold(const float* __restrict__ outA,
                                               float* __restrict__ out) {
  int idx = blockIdx.x * 256 + threadIdx.x;
  if (idx >= B * C * H * W) return;
  int q = idx % W, t = idx / W;
  int p = t % H, t2 = t / H;
  int c = t2 % C, b = t2 / C;
  float s = 0.f;
#pragma unroll
  for (int ky = 0; ky < K; ++ky) {
    int iy = p - ky;
    if (iy < 0 || iy >= NH) continue;
#pragma unroll
    for (int kx = 0; kx < K; ++kx) {
      int jx = q - kx;
      if (jx < 0 || jx >= NW) continue;
      size_t o = ((size_t)(b * KSP + c * 49 + ky * 7 + kx)) * NPAD + iy * NW + jx;
      s += outA[o];
    }
  }
  int cy = min(p, 6) - max(0, p - 56) + 1;
  int cx = min(q, 6) - max(0, q - 56) + 1;
  out[idx] = s / (float)(cy * cx);
}

extern "C" void kernel_launch(void* const* d_in, const int* in_sizes, int n_in,
                              void* d_out, int out_size, void* d_ws, size_t ws_size,
                              hipStream_t stream) {
  const float* x = (const float*)d_in[0];
  const float* y = (const float*)d_in[1];
  const float* w1 = (const float*)d_in[2];
  const float* b1 = (const float*)d_in[3];
  const float* w2 = (const float*)d_in[4];
  const float* b2 = (const float*)d_in[5];
  float* ws = (float*)d_ws;
  float* out = (float*)d_out;

  float* Xr = ws + OFF_XR;
  unsigned short* Xib = (unsigned short*)(ws + OFF_XIB);
  float* sq = ws + OFF_SQ;
  float* hd = ws + OFF_HD;
  float* blk = ws + OFF_BLK;
  float* dinv = ws + OFF_DI;
  float* bimg = ws + OFF_BIMG;
  float* att = ws + OFF_ATT;
  float* outA = ws + OFF_OUTA;

  hipMemsetAsync(outA, 0, SZ_X * sizeof(float), stream);

  nl_block<<<(B * H * W + 255) / 256, 256, 0, stream>>>(x, y, bimg);
  nl_im2col<<<(int)((2 * SZ_X + 255) / 256), 256, 0, stream>>>(x, y, ws);
  nl_blkp<<<(B * NPAD + 255) / 256, 256, 0, stream>>>(bimg, blk);
  nl_sqh<<<(B * NPAD + 255) / 256, 256, 0, stream>>>(Xr, w1, b1, w2, b2, sq, hd);
  nl_gemm1<<<dim3(NPAD / 128, NPAD / 128, B), 256, 0, stream>>>(Xr, sq, hd, att);
  nl_ssum<<<dim3(NPAD, B), 256, 0, stream>>>(att, blk, dinv);
  nl_gemm2<<<dim3(NPAD / 128, SPLITS, B), 256, 0, stream>>>(att, Xib, dinv, blk, outA);
  nl_fold<<<(B * C * H * W + 255) / 256, 256, 0, stream>>>(outA, out);
}